// Round 6
// baseline (360.762 us; speedup 1.0000x reference)
//
#include <hip/hip_runtime.h>
#include <hip/hip_bf16.h>
#include <hip/hip_fp16.h>
#include <math.h>

// Problem dims
#define B 64
#define S 2048
#define E 512
#define HD 512
#define TD 128
#define M_TOT (B*S)

// Workspace layout (in floats)
#define OFF_MASK   0                        // B*S
#define OFF_CTXP   (OFF_MASK + B*S)         // 8*B*E
#define OFF_LENP   (OFF_CTXP + 8*B*E)       // 8*B
#define OFF_CB     (OFF_LENP + 8*B)         // B*HD
#define OFF_REPP   (OFF_CB + B*HD)          // 8*B*E
#define OFF_SCP    (OFF_REPP + 8*B*E)       // 4*B*S score partials (4 N-chunks)
#define OFF_WPK    (OFF_SCP + 4*B*S)        // 262144 fp16 = 131072 floats (W packed)

typedef __attribute__((ext_vector_type(8))) short short8;
typedef __attribute__((ext_vector_type(4))) float f32x4;

__device__ inline unsigned int f2hu(float x) {
    __half h = __float2half(x);
    unsigned short u; __builtin_memcpy(&u, &h, 2); return (unsigned int)u;
}

// fast tanh: exact saturation, ~1e-6 rel err, no NaN (e in (0,1])
__device__ inline float fast_tanh(float x) {
    float a = fabsf(x);
    float e = __expf(-2.0f * a);
    float r = (1.0f - e) / (1.0f + e);
    return copysignf(r, x);
}

// ---------------------------------------------------------------------------
// k0: pack top half of W_att into MFMA B-fragment layout, fp16.
// 16x16x32 f16 B-frag: lane l holds B[k=(l>>4)*8+j][col=l&15].
// Wpk[kstep][fl(32)][lane(64)][j(8)], fl = h>>4
// ---------------------------------------------------------------------------
__global__ __launch_bounds__(256)
void k0_pack(const float* __restrict__ W_att, unsigned short* __restrict__ Wpk)
{
    int tid = blockIdx.x*256 + threadIdx.x;   // 262144 total
    int e = tid >> 9, h = tid & 511;
    float w = W_att[(size_t)e*HD + h];
    int kstep = e >> 5, kb = (e >> 3) & 3, j = e & 7, f = h >> 4, l15 = h & 15;
    size_t dst = ((((size_t)kstep*32 + f)*64) + kb*16 + l15)*8 + j;
    Wpk[dst] = (unsigned short)f2hu(w);
}

// ---------------------------------------------------------------------------
// K1: mask, column partial sums, lengths
// ---------------------------------------------------------------------------
__global__ __launch_bounds__(256)
void k1_maskcol(const float* __restrict__ words, float* __restrict__ mask,
                float* __restrict__ ctxp, float* __restrict__ lenp)
{
    int bid = blockIdx.x;            // 512 = B * 8
    int b = bid >> 3, ch = bid & 7;
    int t = threadIdx.x;
    int w = t >> 6, l = t & 63;
    __shared__ __align__(16) float colred[4][E];
    __shared__ float lenred[4];
    const float* base = words + (size_t)(b * S + ch * 256) * E;
    float4 c0 = make_float4(0.f,0.f,0.f,0.f), c1 = make_float4(0.f,0.f,0.f,0.f);
    float wlen = 0.0f;
    for (int r = w; r < 256; r += 4) {
        const float* row = base + (size_t)r * E;
        float4 a  = *(const float4*)(row + 4*l);
        float4 bb = *(const float4*)(row + 256 + 4*l);
        float rs = a.x+a.y+a.z+a.w + bb.x+bb.y+bb.z+bb.w;
        #pragma unroll
        for (int m = 1; m < 64; m <<= 1) rs += __shfl_xor(rs, m);
        c0.x += a.x;  c0.y += a.y;  c0.z += a.z;  c0.w += a.w;
        c1.x += bb.x; c1.y += bb.y; c1.z += bb.z; c1.w += bb.w;
        if (l == 0) {
            float mv = (rs != 0.0f) ? 1.0f : 0.0f;
            mask[(size_t)b*S + ch*256 + r] = mv;
            wlen += mv;
        }
    }
    *(float4*)&colred[w][4*l]       = c0;
    *(float4*)&colred[w][256 + 4*l] = c1;
    if (l == 0) lenred[w] = wlen;
    __syncthreads();
    float s1 = colred[0][t]+colred[1][t]+colred[2][t]+colred[3][t];
    float s2 = colred[0][t+256]+colred[1][t+256]+colred[2][t+256]+colred[3][t+256];
    size_t o = ((size_t)ch * B + b) * E;
    ctxp[o + t]       = s1;
    ctxp[o + t + 256] = s2;
    if (t == 0) lenp[ch*B + b] = lenred[0]+lenred[1]+lenred[2]+lenred[3];
}

// ---------------------------------------------------------------------------
// K2: cb[b,h] = b_att[h] + context_b . W_att[E:, h]
// ---------------------------------------------------------------------------
__global__ __launch_bounds__(256)
void k2_cb(const float* __restrict__ W_att, const float* __restrict__ b_att,
           const float* __restrict__ ctxp, const float* __restrict__ lenp,
           float* __restrict__ cb)
{
    int bid = blockIdx.x;            // 128
    int b = bid >> 1, hc = bid & 1;
    int t = threadIdx.x;
    __shared__ float ctxL[E];
    float len = 0.f;
    #pragma unroll
    for (int k = 0; k < 8; ++k) len += lenp[k*B + b];
    float inv = 1.0f / len;
    for (int c = t; c < E; c += 256) {
        float sv = 0.f;
        #pragma unroll
        for (int k = 0; k < 8; ++k) sv += ctxp[((size_t)k*B + b)*E + c];
        ctxL[c] = sv * inv;
    }
    __syncthreads();
    int h = hc*256 + t;
    const float* Wb = W_att + (size_t)E * HD;
    float a0 = b_att[h], a1 = 0.f, a2 = 0.f, a3 = 0.f;
    #pragma unroll 4
    for (int e = 0; e < E; e += 4) {
        a0 += ctxL[e]   * Wb[(size_t)e*HD + h];
        a1 += ctxL[e+1] * Wb[(size_t)(e+1)*HD + h];
        a2 += ctxL[e+2] * Wb[(size_t)(e+2)*HD + h];
        a3 += ctxL[e+3] * Wb[(size_t)(e+3)*HD + h];
    }
    cb[(size_t)b*HD + h] = (a0 + a1) + (a2 + a3);
}

// ---------------------------------------------------------------------------
// K3: fp16 MFMA scores. Block tile 128(M) x 128(N per nc), nc=4, BK=32.
// 8 waves = 2 wr x 4 wc, wave = 64x32 -> acc 32 regs; total ~100 regs/wave
// -> 2 blocks/CU (16 waves). A: LDS dbuf 2x8KB, frag-packed, 2-deep global
// prefetch. B: global->reg from packed Wpk (L2-resident), 2-deep prefetch.
// Fully unrolled K loop so prefetch parities are static.
// ---------------------------------------------------------------------------
__global__ __launch_bounds__(512, 4)
void k3_scores(const float* __restrict__ words,
               const unsigned short* __restrict__ Wpk,
               const float* __restrict__ cb, const float* __restrict__ v,
               float* __restrict__ scp)
{
    __shared__ __align__(16) unsigned char smem[16384];   // A dbuf: 2 x 8KB
    int bid = blockIdx.x;             // 4096 = 1024 mtiles * 4 nchunks
    int mt = bid >> 2, nc = bid & 3;
    int m0 = mt * 128;
    int b  = m0 >> 11;                // S = 2048
    int t = threadIdx.x;
    int lane = t & 63, wid = t >> 6;
    int wr = wid >> 2, wc = wid & 3;  // 2 row-groups x 4 col-groups

    f32x4 acc[4][2];
    #pragma unroll
    for (int i = 0; i < 4; ++i)
        #pragma unroll
        for (int j = 0; j < 2; ++j) acc[i][j] = (f32x4)0.0f;

    // ---- A staging: thread t -> row r = t>>2, k-quarter kq = t&3 (8 floats)
    int r = t >> 2, kq = t & 3;
    const float* aSrc = words + (size_t)(m0 + r)*E + kq*8;
    int abase = (r >> 4)*1024 + kq*256 + (r & 15)*16;

    // ---- B fragment base: frag fl = nc*8 + wc*2 + cf
    const unsigned short* bBase = Wpk + (((size_t)(nc*8 + wc*2))*64 + lane)*8;
#define LDB(ks,cf) (*(const short8*)(bBase + ((size_t)(ks)*32 + (cf))*512))

    float4 R0a, R0b, R1a, R1b, Rta, Rtb;
#define LOADA(Ra, Rb, ks) do { const float* _s = aSrc + (ks)*32; \
        Ra = *(const float4*)(_s); Rb = *(const float4*)(_s + 4); } while(0)
#define STAGEA(buf, Ra, Rb) do { \
        unsigned int u0 = f2hu(Ra.x) | (f2hu(Ra.y) << 16); \
        unsigned int u1 = f2hu(Ra.z) | (f2hu(Ra.w) << 16); \
        unsigned int u2 = f2hu(Rb.x) | (f2hu(Rb.y) << 16); \
        unsigned int u3 = f2hu(Rb.z) | (f2hu(Rb.w) << 16); \
        *(uint4*)&(buf)[abase] = make_uint4(u0, u1, u2, u3); } while(0)

    unsigned char* sm0 = smem;
    unsigned char* sm1 = smem + 8192;

    // ---- prologue
    LOADA(Rta, Rtb, 0);
    STAGEA(sm0, Rta, Rtb);          // buf0 <- kstep 0
    LOADA(R1a, R1b, 1);             // consumed (staged) at k=0
    LOADA(R0a, R0b, 2);             // consumed (staged) at k=1
    short8 bE[2], bO[2];
    bE[0] = LDB(0, 0); bE[1] = LDB(0, 1);
    bO[0] = LDB(1, 0); bO[1] = LDB(1, 1);
    __syncthreads();

#define KBODY(k, BUFC, BUFN, RSa, RSb, BF) do { \
        short8 ah[4]; \
        _Pragma("unroll") \
        for (int rf = 0; rf < 4; ++rf) \
            ah[rf] = *(const short8*)&(BUFC)[(wr*4 + rf)*1024 + lane*16]; \
        if ((k) < 15) STAGEA(BUFN, RSa, RSb); \
        if ((k) < 13) LOADA(RSa, RSb, (k) + 3); \
        _Pragma("unroll") \
        for (int cf = 0; cf < 2; ++cf) { \
            _Pragma("unroll") \
            for (int rf = 0; rf < 4; ++rf) \
                acc[rf][cf] = __builtin_amdgcn_mfma_f32_16x16x32_f16(ah[rf], BF[cf], acc[rf][cf], 0, 0, 0); \
            if ((k) < 14) BF[cf] = LDB((k) + 2, cf); \
        } \
        __syncthreads(); } while(0)

    #pragma unroll
    for (int kk = 0; kk < 8; ++kk) {
        KBODY(2*kk,     sm0, sm1, R1a, R1b, bE);
        KBODY(2*kk + 1, sm1, sm0, R0a, R0b, bO);
    }
#undef KBODY
#undef LOADA
#undef STAGEA
#undef LDB

    // ---- epilogue: tanh(+cb)*v, reduce over cols
    float ssum[4][4];
    #pragma unroll
    for (int i = 0; i < 4; ++i)
        #pragma unroll
        for (int rr = 0; rr < 4; ++rr) ssum[i][rr] = 0.f;

    #pragma unroll
    for (int cf = 0; cf < 2; ++cf) {
        int col = nc*128 + wc*32 + cf*16 + (lane & 15);
        float cbv = cb[(size_t)b*HD + col];
        float vv  = v[col];
        #pragma unroll
        for (int rf = 0; rf < 4; ++rf)
            #pragma unroll
            for (int rr = 0; rr < 4; ++rr)
                ssum[rf][rr] += fast_tanh(acc[rf][cf][rr] + cbv) * vv;
    }
    #pragma unroll
    for (int m = 1; m < 16; m <<= 1)
        #pragma unroll
        for (int rf = 0; rf < 4; ++rf)
            #pragma unroll
            for (int rr = 0; rr < 4; ++rr)
                ssum[rf][rr] += __shfl_xor(ssum[rf][rr], m);

    float* scr = (float*)smem;   // 512 floats; loop ended with barrier
    if ((lane & 15) == 0) {
        #pragma unroll
        for (int rf = 0; rf < 4; ++rf)
            #pragma unroll
            for (int rr = 0; rr < 4; ++rr)
                scr[wc*128 + wr*64 + rf*16 + (lane >> 4)*4 + rr] = ssum[rf][rr];
    }
    __syncthreads();
    if (t < 128) {
        float val = (scr[t] + scr[128 + t]) + (scr[256 + t] + scr[384 + t]);
        scp[(size_t)nc*M_TOT + m0 + t] = val;
    }
}

// ---------------------------------------------------------------------------
// K4 (fused softstats + rep): block (b, ch). Recompute batch softmax stats
// from scp (redundant x8, cheap L2 reads), then weighted col-sum of chunk.
// ---------------------------------------------------------------------------
__global__ __launch_bounds__(256)
void k4_rep(const float* __restrict__ words, const float* __restrict__ scp,
            const float* __restrict__ mask, float* __restrict__ repp)
{
    int bid = blockIdx.x;            // 512
    int b = bid >> 3, ch = bid & 7;
    int t = threadIdx.x;
    __shared__ float red[256];
    __shared__ float wrow[256];

    float xs[8];
    float mx = -1e30f;
    #pragma unroll
    for (int k = 0; k < 8; ++k) {
        size_t m = (size_t)b*S + 256*k + t;
        float x = (scp[m] + scp[(size_t)M_TOT + m])
                + (scp[(size_t)2*M_TOT + m] + scp[(size_t)3*M_TOT + m]);
        x = (mask[m] > 0.0f) ? x : -1e30f;
        xs[k] = x; mx = fmaxf(mx, x);
    }
    red[t] = mx; __syncthreads();
    for (int off = 128; off > 0; off >>= 1) {
        if (t < off) red[t] = fmaxf(red[t], red[t+off]);
        __syncthreads();
    }
    float gmax = red[0]; __syncthreads();
    float se = 0.f;
    #pragma unroll
    for (int k = 0; k < 8; ++k) se += expf(xs[k] - gmax);
    red[t] = se; __syncthreads();
    for (int off = 128; off > 0; off >>= 1) {
        if (t < off) red[t] += red[t+off];
        __syncthreads();
    }
    float den = red[0];
    wrow[t] = expf(xs[ch] - gmax) / den;    // this chunk's row weight
    __syncthreads();

    const float* base = words + (size_t)(b*S + ch*256)*E + 2*t;
    float2 acc = make_float2(0.f, 0.f);
    #pragma unroll 4
    for (int rr = 0; rr < 256; ++rr) {
        float2 wv = *(const float2*)(base + (size_t)rr*E);
        float a = wrow[rr];
        acc.x = fmaf(a, wv.x, acc.x);
        acc.y = fmaf(a, wv.y, acc.y);
    }
    size_t o = ((size_t)ch*B + b)*E + 2*t;
    *(float2*)&repp[o] = acc;
}

// ---------------------------------------------------------------------------
// K5 (fused MLP): one block per batch. LDS ping-pong between layers.
// ---------------------------------------------------------------------------
__global__ __launch_bounds__(256)
void k5_mlp(const float* __restrict__ repp,
            const float* __restrict__ W1, const float* __restrict__ b1,
            const float* __restrict__ W2, const float* __restrict__ b2,
            const float* __restrict__ W3, const float* __restrict__ b3,
            float* __restrict__ out)
{
    int b = blockIdx.x;              // 64
    int t = threadIdx.x;             // 256
    __shared__ float xL[HD];
    __shared__ float yL[HD];
    for (int c = t; c < E; c += 256) {
        float sv = 0.f;
        #pragma unroll
        for (int k = 0; k < 8; ++k) sv += repp[((size_t)k*B + b)*E + c];
        xL[c] = sv;
    }
    __syncthreads();
    #pragma unroll
    for (int oo = 0; oo < 2; ++oo) {
        int h = oo*256 + t;
        float a0 = b1[h], a1 = 0.f, a2 = 0.f, a3 = 0.f;
        #pragma unroll 4
        for (int e = 0; e < E; e += 4) {
            a0 += xL[e]   * W1[(size_t)e*HD + h];
            a1 += xL[e+1] * W1[(size_t)(e+1)*HD + h];
            a2 += xL[e+2] * W1[(size_t)(e+2)*HD + h];
            a3 += xL[e+3] * W1[(size_t)(e+3)*HD + h];
        }
        yL[h] = fmaxf((a0 + a1) + (a2 + a3), 0.f);
    }
    __syncthreads();
    float l2v[2];
    #pragma unroll
    for (int oo = 0; oo < 2; ++oo) {
        int h = oo*256 + t;
        float a0 = b2[h], a1 = 0.f, a2 = 0.f, a3 = 0.f;
        #pragma unroll 4
        for (int e = 0; e < HD; e += 4) {
            a0 += yL[e]   * W2[(size_t)e*HD + h];
            a1 += yL[e+1] * W2[(size_t)(e+1)*HD + h];
            a2 += yL[e+2] * W2[(size_t)(e+2)*HD + h];
            a3 += yL[e+3] * W2[(size_t)(e+3)*HD + h];
        }
        l2v[oo] = fmaxf((a0 + a1) + (a2 + a3), 0.f);
    }
    __syncthreads();
    xL[t] = l2v[0]; xL[256 + t] = l2v[1];
    __syncthreads();
    if (t < TD) {
        float a0 = b3[t], a1 = 0.f, a2 = 0.f, a3 = 0.f;
        #pragma unroll 4
        for (int e = 0; e < HD; e += 4) {
            a0 += xL[e]   * W3[(size_t)e*TD + t];
            a1 += xL[e+1] * W3[(size_t)(e+1)*TD + t];
            a2 += xL[e+2] * W3[(size_t)(e+2)*TD + t];
            a3 += xL[e+3] * W3[(size_t)(e+3)*TD + t];
        }
        out[(size_t)b*TD + t] = (a0 + a1) + (a2 + a3);
    }
}

extern "C" void kernel_launch(void* const* d_in, const int* in_sizes, int n_in,
                              void* d_out, int out_size, void* d_ws, size_t ws_size,
                              hipStream_t stream)
{
    const float* words = (const float*)d_in[0];
    const float* W_att = (const float*)d_in[1];
    const float* b_att = (const float*)d_in[2];
    const float* v     = (const float*)d_in[3];
    const float* W1    = (const float*)d_in[4];
    const float* b1    = (const float*)d_in[5];
    const float* W2    = (const float*)d_in[6];
    const float* b2    = (const float*)d_in[7];
    const float* W3    = (const float*)d_in[8];
    const float* b3    = (const float*)d_in[9];
    (void)in_sizes; (void)n_in; (void)out_size; (void)ws_size;

    float* ws   = (float*)d_ws;
    float* mask = ws + OFF_MASK;
    float* ctxp = ws + OFF_CTXP;
    float* lenp = ws + OFF_LENP;
    float* cb   = ws + OFF_CB;
    float* repp = ws + OFF_REPP;
    float* scp  = ws + OFF_SCP;
    unsigned short* Wpk = (unsigned short*)(ws + OFF_WPK);
    float* out  = (float*)d_out;

    hipLaunchKernelGGL(k0_pack,    dim3(1024), dim3(256), 0, stream, W_att, Wpk);
    hipLaunchKernelGGL(k1_maskcol, dim3(B*8),  dim3(256), 0, stream, words, mask, ctxp, lenp);
    hipLaunchKernelGGL(k2_cb,      dim3(B*2),  dim3(256), 0, stream, W_att, b_att, ctxp, lenp, cb);
    hipLaunchKernelGGL(k3_scores,  dim3(4096), dim3(512), 0, stream, words, Wpk, cb, v, scp);
    hipLaunchKernelGGL(k4_rep,     dim3(B*8),  dim3(256), 0, stream, words, scp, mask, repp);
    hipLaunchKernelGGL(k5_mlp,     dim3(B),    dim3(256), 0, stream, repp, W1, b1, W2, b2, W3, b3, out);
}

// Round 7
// 358.706 us; speedup vs baseline: 1.0057x; 1.0057x over previous
//
#include <hip/hip_runtime.h>
#include <hip/hip_bf16.h>
#include <hip/hip_fp16.h>
#include <math.h>

// Problem dims
#define B 64
#define S 2048
#define E 512
#define HD 512
#define TD 128
#define M_TOT (B*S)

// Workspace layout (in floats)
#define OFF_MASK   0                        // B*S
#define OFF_CTXP   (OFF_MASK + B*S)         // 8*B*E
#define OFF_LENP   (OFF_CTXP + 8*B*E)       // 8*B
#define OFF_CB     (OFF_LENP + 8*B)         // B*HD
#define OFF_REPP   (OFF_CB + B*HD)          // 8*B*E
#define OFF_SC     (OFF_REPP + 8*B*E)       // B*S raw scores (complete, unmasked)
#define OFF_WPK    (OFF_SC + B*S)           // 262144 fp16 = 131072 floats (W packed)

typedef __attribute__((ext_vector_type(8))) short short8;
typedef __attribute__((ext_vector_type(4))) float f32x4;

__device__ inline unsigned int f2hu(float x) {
    __half h = __float2half(x);
    unsigned short u; __builtin_memcpy(&u, &h, 2); return (unsigned int)u;
}

// fast tanh: exact saturation, ~1e-6 rel err, no NaN (e in (0,1])
__device__ inline float fast_tanh(float x) {
    float a = fabsf(x);
    float e = __expf(-2.0f * a);
    float r = (1.0f - e) / (1.0f + e);
    return copysignf(r, x);
}

// ---------------------------------------------------------------------------
// k0: pack top half of W_att into MFMA B-fragment layout, fp16.
// 16x16x32 f16 B-frag: lane l holds B[k=(l>>4)*8+j][col=l&15].
// Wpk[kstep][fl(32)][lane(64)][j(8)], fl = h>>4
// ---------------------------------------------------------------------------
__global__ __launch_bounds__(256)
void k0_pack(const float* __restrict__ W_att, unsigned short* __restrict__ Wpk)
{
    int tid = blockIdx.x*256 + threadIdx.x;   // 262144 total
    int e = tid >> 9, h = tid & 511;
    float w = W_att[(size_t)e*HD + h];
    int kstep = e >> 5, kb = (e >> 3) & 3, j = e & 7, f = h >> 4, l15 = h & 15;
    size_t dst = ((((size_t)kstep*32 + f)*64) + kb*16 + l15)*8 + j;
    Wpk[dst] = (unsigned short)f2hu(w);
}

// ---------------------------------------------------------------------------
// K1: mask, column partial sums, lengths
// ---------------------------------------------------------------------------
__global__ __launch_bounds__(256)
void k1_maskcol(const float* __restrict__ words, float* __restrict__ mask,
                float* __restrict__ ctxp, float* __restrict__ lenp)
{
    int bid = blockIdx.x;            // 512 = B * 8
    int b = bid >> 3, ch = bid & 7;
    int t = threadIdx.x;
    int w = t >> 6, l = t & 63;
    __shared__ __align__(16) float colred[4][E];
    __shared__ float lenred[4];
    const float* base = words + (size_t)(b * S + ch * 256) * E;
    float4 c0 = make_float4(0.f,0.f,0.f,0.f), c1 = make_float4(0.f,0.f,0.f,0.f);
    float wlen = 0.0f;
    for (int r = w; r < 256; r += 4) {
        const float* row = base + (size_t)r * E;
        float4 a  = *(const float4*)(row + 4*l);
        float4 bb = *(const float4*)(row + 256 + 4*l);
        float rs = a.x+a.y+a.z+a.w + bb.x+bb.y+bb.z+bb.w;
        #pragma unroll
        for (int m = 1; m < 64; m <<= 1) rs += __shfl_xor(rs, m);
        c0.x += a.x;  c0.y += a.y;  c0.z += a.z;  c0.w += a.w;
        c1.x += bb.x; c1.y += bb.y; c1.z += bb.z; c1.w += bb.w;
        if (l == 0) {
            float mv = (rs != 0.0f) ? 1.0f : 0.0f;
            mask[(size_t)b*S + ch*256 + r] = mv;
            wlen += mv;
        }
    }
    *(float4*)&colred[w][4*l]       = c0;
    *(float4*)&colred[w][256 + 4*l] = c1;
    if (l == 0) lenred[w] = wlen;
    __syncthreads();
    float s1 = colred[0][t]+colred[1][t]+colred[2][t]+colred[3][t];
    float s2 = colred[0][t+256]+colred[1][t+256]+colred[2][t+256]+colred[3][t+256];
    size_t o = ((size_t)ch * B + b) * E;
    ctxp[o + t]       = s1;
    ctxp[o + t + 256] = s2;
    if (t == 0) lenp[ch*B + b] = lenred[0]+lenred[1]+lenred[2]+lenred[3];
}

// ---------------------------------------------------------------------------
// K2: cb[b,h] = b_att[h] + context_b . W_att[E:, h]
// ---------------------------------------------------------------------------
__global__ __launch_bounds__(256)
void k2_cb(const float* __restrict__ W_att, const float* __restrict__ b_att,
           const float* __restrict__ ctxp, const float* __restrict__ lenp,
           float* __restrict__ cb)
{
    int bid = blockIdx.x;            // 128
    int b = bid >> 1, hc = bid & 1;
    int t = threadIdx.x;
    __shared__ float ctxL[E];
    float len = 0.f;
    #pragma unroll
    for (int k = 0; k < 8; ++k) len += lenp[k*B + b];
    float inv = 1.0f / len;
    for (int c = t; c < E; c += 256) {
        float sv = 0.f;
        #pragma unroll
        for (int k = 0; k < 8; ++k) sv += ctxp[((size_t)k*B + b)*E + c];
        ctxL[c] = sv * inv;
    }
    __syncthreads();
    int h = hc*256 + t;
    const float* Wb = W_att + (size_t)E * HD;
    float a0 = b_att[h], a1 = 0.f, a2 = 0.f, a3 = 0.f;
    #pragma unroll 4
    for (int e = 0; e < E; e += 4) {
        a0 += ctxL[e]   * Wb[(size_t)e*HD + h];
        a1 += ctxL[e+1] * Wb[(size_t)(e+1)*HD + h];
        a2 += ctxL[e+2] * Wb[(size_t)(e+2)*HD + h];
        a3 += ctxL[e+3] * Wb[(size_t)(e+3)*HD + h];
    }
    cb[(size_t)b*HD + h] = (a0 + a1) + (a2 + a3);
}

// ---------------------------------------------------------------------------
// K3: fp16 MFMA scores. Block tile 64(M) x 512(N) -> A read ONCE from HBM.
// 8 waves = 2 wr x 4 wc, wave 32x128 -> acc[2][8] = 64 regs.
// A: LDS dbuf 2x8KB, BK=64/stage (2 MFMA ksteps), 8 barriers total.
//    Staging map derived from LINEAR lds pos (lane -> lane*16): zero write
//    conflicts; global reads remain 128B-contiguous per row.
// B: global->reg from packed Wpk (L2-resident), reload after last use.
// Writes COMPLETE raw scores (nc=1) -> no partial-combine pass.
// ---------------------------------------------------------------------------
__global__ __launch_bounds__(512, 3)
void k3_scores(const float* __restrict__ words,
               const unsigned short* __restrict__ Wpk,
               const float* __restrict__ cb, const float* __restrict__ v,
               float* __restrict__ sc)
{
    __shared__ __align__(16) unsigned char smem[16384];   // A dbuf: 2 x 8KB
    int mt = blockIdx.x;              // 2048 mtiles of 64 rows
    int m0 = mt * 64;
    int b  = m0 >> 11;                // S = 2048
    int t = threadIdx.x;
    int lane = t & 63, wid = t >> 6;
    int wr = wid >> 2, wc = wid & 3;  // 2 row-groups x 4 col-groups

    f32x4 acc[2][8];
    #pragma unroll
    for (int i = 0; i < 2; ++i)
        #pragma unroll
        for (int j = 0; j < 8; ++j) acc[i][j] = (f32x4)0.0f;

    // ---- A staging map (from linear LDS pos p = t*16):
    // ks = t>>8 (which 32-k half), F = (t>>6)&3 (frag-row), kb = (t>>4)&3,
    // l15 = t&15; row = F*16+l15; k0 = ks*32 + kb*8 (8 consecutive floats).
    {
    }
    int sks = t >> 8, sF = (t >> 6) & 3, skb = (t >> 4) & 3, sl15 = t & 15;
    int srow = sF*16 + sl15;
    const float* aSrc = words + (size_t)(m0 + srow)*E + sks*32 + skb*8;

    // ---- B fragment base: frag fl = wc*8 + cf  (all 512 cols in-block)
    const unsigned short* bBase = Wpk + (((size_t)(wc*8))*64 + lane)*8;
#define LDB(kst,cf) (*(const short8*)(bBase + ((size_t)(kst)*32 + (cf))*512))

    float4 pa0, pa1, qa0, qa1;
#define LOADA(P0, P1, s) do { const float* _s = aSrc + (s)*64; \
        P0 = *(const float4*)(_s); P1 = *(const float4*)(_s + 4); } while(0)
#define STAGEA(buf, P0, P1) do { \
        unsigned int u0 = f2hu(P0.x) | (f2hu(P0.y) << 16); \
        unsigned int u1 = f2hu(P0.z) | (f2hu(P0.w) << 16); \
        unsigned int u2 = f2hu(P1.x) | (f2hu(P1.y) << 16); \
        unsigned int u3 = f2hu(P1.z) | (f2hu(P1.w) << 16); \
        *(uint4*)&(buf)[t*16] = make_uint4(u0, u1, u2, u3); } while(0)

    unsigned char* sm0 = smem;
    unsigned char* sm1 = smem + 8192;

    // ---- prologue: stage 0 -> sm0; pa <- stage1, qa <- stage2; B kstep0
    LOADA(pa0, pa1, 0);
    STAGEA(sm0, pa0, pa1);
    LOADA(pa0, pa1, 1);
    LOADA(qa0, qa1, 2);
    short8 bcur[8];
    #pragma unroll
    for (int cf = 0; cf < 8; ++cf) bcur[cf] = LDB(0, cf);
    __syncthreads();

    // one MFMA kstep (K=32) from stage buffer BUFC, sub-tile ksub
#define KSUB(kst, BUFC, ksub) do { \
        short8 ah0 = *(const short8*)&(BUFC)[(ksub)*4096 + (wr*2    )*1024 + lane*16]; \
        short8 ah1 = *(const short8*)&(BUFC)[(ksub)*4096 + (wr*2 + 1)*1024 + lane*16]; \
        _Pragma("unroll") \
        for (int cf = 0; cf < 8; ++cf) { \
            acc[0][cf] = __builtin_amdgcn_mfma_f32_16x16x32_f16(ah0, bcur[cf], acc[0][cf], 0, 0, 0); \
            acc[1][cf] = __builtin_amdgcn_mfma_f32_16x16x32_f16(ah1, bcur[cf], acc[1][cf], 0, 0, 0); \
            if ((kst) < 15) bcur[cf] = LDB((kst) + 1, cf); \
        } } while(0)

    // stage body: consume BUFC (stage s), stage s+1 into BUFN, load s+3
#define SBODY(s, BUFC, BUFN, P0, P1) do { \
        if ((s) < 7) STAGEA(BUFN, P0, P1); \
        if ((s) < 5) LOADA(P0, P1, (s) + 3); \
        KSUB(2*(s),     BUFC, 0); \
        KSUB(2*(s) + 1, BUFC, 1); \
        __syncthreads(); } while(0)

    SBODY(0, sm0, sm1, pa0, pa1);
    SBODY(1, sm1, sm0, qa0, qa1);
    SBODY(2, sm0, sm1, pa0, pa1);
    SBODY(3, sm1, sm0, qa0, qa1);
    SBODY(4, sm0, sm1, pa0, pa1);
    SBODY(5, sm1, sm0, qa0, qa1);
    SBODY(6, sm0, sm1, pa0, pa1);
    SBODY(7, sm1, sm0, qa0, qa1);
#undef SBODY
#undef KSUB
#undef LOADA
#undef STAGEA
#undef LDB

    // ---- epilogue: tanh(+cb)*v, reduce over this wave's 128 cols
    float ssum[2][4];
    #pragma unroll
    for (int i = 0; i < 2; ++i)
        #pragma unroll
        for (int rr = 0; rr < 4; ++rr) ssum[i][rr] = 0.f;

    #pragma unroll
    for (int cf = 0; cf < 8; ++cf) {
        int col = wc*128 + cf*16 + (lane & 15);
        float cbv = cb[(size_t)b*HD + col];
        float vv  = v[col];
        #pragma unroll
        for (int rf = 0; rf < 2; ++rf)
            #pragma unroll
            for (int rr = 0; rr < 4; ++rr)
                ssum[rf][rr] += fast_tanh(acc[rf][cf][rr] + cbv) * vv;
    }
    #pragma unroll
    for (int m = 1; m < 16; m <<= 1)
        #pragma unroll
        for (int rf = 0; rf < 2; ++rf)
            #pragma unroll
            for (int rr = 0; rr < 4; ++rr)
                ssum[rf][rr] += __shfl_xor(ssum[rf][rr], m);

    float* scr = (float*)smem;   // 4 wc x 64 rows; loop ended with barrier
    if ((lane & 15) == 0) {
        #pragma unroll
        for (int rf = 0; rf < 2; ++rf)
            #pragma unroll
            for (int rr = 0; rr < 4; ++rr)
                scr[wc*64 + wr*32 + rf*16 + (lane >> 4)*4 + rr] = ssum[rf][rr];
    }
    __syncthreads();
    if (t < 64) {
        float val = (scr[t] + scr[64 + t]) + (scr[128 + t] + scr[192 + t]);
        sc[(size_t)m0 + t] = val;
    }
}

// ---------------------------------------------------------------------------
// K4 (fused softstats + rep): block (b, ch). Recompute batch softmax stats
// from sc (redundant x8, cheap L2 reads), then weighted col-sum of chunk.
// ---------------------------------------------------------------------------
__global__ __launch_bounds__(256)
void k4_rep(const float* __restrict__ words, const float* __restrict__ sc,
            const float* __restrict__ mask, float* __restrict__ repp)
{
    int bid = blockIdx.x;            // 512
    int b = bid >> 3, ch = bid & 7;
    int t = threadIdx.x;
    __shared__ float red[256];
    __shared__ float wrow[256];

    float xs[8];
    float mx = -1e30f;
    #pragma unroll
    for (int k = 0; k < 8; ++k) {
        size_t m = (size_t)b*S + 256*k + t;
        float x = sc[m];
        x = (mask[m] > 0.0f) ? x : -1e30f;
        xs[k] = x; mx = fmaxf(mx, x);
    }
    red[t] = mx; __syncthreads();
    for (int off = 128; off > 0; off >>= 1) {
        if (t < off) red[t] = fmaxf(red[t], red[t+off]);
        __syncthreads();
    }
    float gmax = red[0]; __syncthreads();
    float se = 0.f;
    #pragma unroll
    for (int k = 0; k < 8; ++k) se += expf(xs[k] - gmax);
    red[t] = se; __syncthreads();
    for (int off = 128; off > 0; off >>= 1) {
        if (t < off) red[t] += red[t+off];
        __syncthreads();
    }
    float den = red[0];
    wrow[t] = expf(xs[ch] - gmax) / den;    // this chunk's row weight
    __syncthreads();

    const float* base = words + (size_t)(b*S + ch*256)*E + 2*t;
    float2 acc = make_float2(0.f, 0.f);
    #pragma unroll 4
    for (int rr = 0; rr < 256; ++rr) {
        float2 wv = *(const float2*)(base + (size_t)rr*E);
        float a = wrow[rr];
        acc.x = fmaf(a, wv.x, acc.x);
        acc.y = fmaf(a, wv.y, acc.y);
    }
    size_t o = ((size_t)ch*B + b)*E + 2*t;
    *(float2*)&repp[o] = acc;
}

// ---------------------------------------------------------------------------
// K5 (fused MLP): one block per batch. LDS ping-pong between layers.
// ---------------------------------------------------------------------------
__global__ __launch_bounds__(256)
void k5_mlp(const float* __restrict__ repp,
            const float* __restrict__ W1, const float* __restrict__ b1,
            const float* __restrict__ W2, const float* __restrict__ b2,
            const float* __restrict__ W3, const float* __restrict__ b3,
            float* __restrict__ out)
{
    int b = blockIdx.x;              // 64
    int t = threadIdx.x;             // 256
    __shared__ float xL[HD];
    __shared__ float yL[HD];
    for (int c = t; c < E; c += 256) {
        float sv = 0.f;
        #pragma unroll
        for (int k = 0; k < 8; ++k) sv += repp[((size_t)k*B + b)*E + c];
        xL[c] = sv;
    }
    __syncthreads();
    #pragma unroll
    for (int oo = 0; oo < 2; ++oo) {
        int h = oo*256 + t;
        float a0 = b1[h], a1 = 0.f, a2 = 0.f, a3 = 0.f;
        #pragma unroll 4
        for (int e = 0; e < E; e += 4) {
            a0 += xL[e]   * W1[(size_t)e*HD + h];
            a1 += xL[e+1] * W1[(size_t)(e+1)*HD + h];
            a2 += xL[e+2] * W1[(size_t)(e+2)*HD + h];
            a3 += xL[e+3] * W1[(size_t)(e+3)*HD + h];
        }
        yL[h] = fmaxf((a0 + a1) + (a2 + a3), 0.f);
    }
    __syncthreads();
    float l2v[2];
    #pragma unroll
    for (int oo = 0; oo < 2; ++oo) {
        int h = oo*256 + t;
        float a0 = b2[h], a1 = 0.f, a2 = 0.f, a3 = 0.f;
        #pragma unroll 4
        for (int e = 0; e < HD; e += 4) {
            a0 += yL[e]   * W2[(size_t)e*HD + h];
            a1 += yL[e+1] * W2[(size_t)(e+1)*HD + h];
            a2 += yL[e+2] * W2[(size_t)(e+2)*HD + h];
            a3 += yL[e+3] * W2[(size_t)(e+3)*HD + h];
        }
        l2v[oo] = fmaxf((a0 + a1) + (a2 + a3), 0.f);
    }
    __syncthreads();
    xL[t] = l2v[0]; xL[256 + t] = l2v[1];
    __syncthreads();
    if (t < TD) {
        float a0 = b3[t], a1 = 0.f, a2 = 0.f, a3 = 0.f;
        #pragma unroll 4
        for (int e = 0; e < HD; e += 4) {
            a0 += xL[e]   * W3[(size_t)e*TD + t];
            a1 += xL[e+1] * W3[(size_t)(e+1)*TD + t];
            a2 += xL[e+2] * W3[(size_t)(e+2)*TD + t];
            a3 += xL[e+3] * W3[(size_t)(e+3)*TD + t];
        }
        out[(size_t)b*TD + t] = (a0 + a1) + (a2 + a3);
    }
}

extern "C" void kernel_launch(void* const* d_in, const int* in_sizes, int n_in,
                              void* d_out, int out_size, void* d_ws, size_t ws_size,
                              hipStream_t stream)
{
    const float* words = (const float*)d_in[0];
    const float* W_att = (const float*)d_in[1];
    const float* b_att = (const float*)d_in[2];
    const float* v     = (const float*)d_in[3];
    const float* W1    = (const float*)d_in[4];
    const float* b1    = (const float*)d_in[5];
    const float* W2    = (const float*)d_in[6];
    const float* b2    = (const float*)d_in[7];
    const float* W3    = (const float*)d_in[8];
    const float* b3    = (const float*)d_in[9];
    (void)in_sizes; (void)n_in; (void)out_size; (void)ws_size;

    float* ws   = (float*)d_ws;
    float* mask = ws + OFF_MASK;
    float* ctxp = ws + OFF_CTXP;
    float* lenp = ws + OFF_LENP;
    float* cb   = ws + OFF_CB;
    float* repp = ws + OFF_REPP;
    float* sc   = ws + OFF_SC;
    unsigned short* Wpk = (unsigned short*)(ws + OFF_WPK);
    float* out  = (float*)d_out;

    hipLaunchKernelGGL(k0_pack,    dim3(1024), dim3(256), 0, stream, W_att, Wpk);
    hipLaunchKernelGGL(k1_maskcol, dim3(B*8),  dim3(256), 0, stream, words, mask, ctxp, lenp);
    hipLaunchKernelGGL(k2_cb,      dim3(B*2),  dim3(256), 0, stream, W_att, b_att, ctxp, lenp, cb);
    hipLaunchKernelGGL(k3_scores,  dim3(2048), dim3(512), 0, stream, words, Wpk, cb, v, sc);
    hipLaunchKernelGGL(k4_rep,     dim3(B*8),  dim3(256), 0, stream, words, sc, mask, repp);
    hipLaunchKernelGGL(k5_mlp,     dim3(B),    dim3(256), 0, stream, repp, W1, b1, W2, b2, W3, b3, out);
}

// Round 8
// 322.126 us; speedup vs baseline: 1.1199x; 1.1136x over previous
//
#include <hip/hip_runtime.h>
#include <hip/hip_bf16.h>
#include <hip/hip_fp16.h>
#include <math.h>

// Problem dims
#define B 64
#define S 2048
#define E 512
#define HD 512
#define TD 128
#define M_TOT (B*S)

// Workspace layout (in floats)
#define OFF_MASK   0                        // B*S
#define OFF_CTXP   (OFF_MASK + B*S)         // 8*B*E
#define OFF_LENP   (OFF_CTXP + 8*B*E)       // 8*B
#define OFF_CB     (OFF_LENP + 8*B)         // B*HD
#define OFF_REPP   (OFF_CB + B*HD)          // 8*B*E
#define OFF_SC     (OFF_REPP + 8*B*E)       // B*S raw scores (complete, unmasked)
#define OFF_WPK    (OFF_SC + B*S)           // 262144 fp16 = 131072 floats (W packed)

typedef __attribute__((ext_vector_type(8))) short short8;
typedef __attribute__((ext_vector_type(4))) float f32x4;

__device__ inline unsigned int f2hu(float x) {
    __half h = __float2half(x);
    unsigned short u; __builtin_memcpy(&u, &h, 2); return (unsigned int)u;
}

// fast tanh: exact saturation, ~1e-6 rel err, no NaN (e in (0,1])
__device__ inline float fast_tanh(float x) {
    float a = fabsf(x);
    float e = __expf(-2.0f * a);
    float r = (1.0f - e) / (1.0f + e);
    return copysignf(r, x);
}

// ---------------------------------------------------------------------------
// k0: pack top half of W_att into MFMA B-fragment layout, fp16.
// 16x16x32 f16 B-frag: lane l holds B[k=(l>>4)*8+j][col=l&15].
// Wpk[kstep][fl(32)][lane(64)][j(8)], fl = h>>4
// ---------------------------------------------------------------------------
__global__ __launch_bounds__(256)
void k0_pack(const float* __restrict__ W_att, unsigned short* __restrict__ Wpk)
{
    int tid = blockIdx.x*256 + threadIdx.x;   // 262144 total
    int e = tid >> 9, h = tid & 511;
    float w = W_att[(size_t)e*HD + h];
    int kstep = e >> 5, kb = (e >> 3) & 3, j = e & 7, f = h >> 4, l15 = h & 15;
    size_t dst = ((((size_t)kstep*32 + f)*64) + kb*16 + l15)*8 + j;
    Wpk[dst] = (unsigned short)f2hu(w);
}

// ---------------------------------------------------------------------------
// K1: mask, column partial sums, lengths
// ---------------------------------------------------------------------------
__global__ __launch_bounds__(256)
void k1_maskcol(const float* __restrict__ words, float* __restrict__ mask,
                float* __restrict__ ctxp, float* __restrict__ lenp)
{
    int bid = blockIdx.x;            // 512 = B * 8
    int b = bid >> 3, ch = bid & 7;
    int t = threadIdx.x;
    int w = t >> 6, l = t & 63;
    __shared__ __align__(16) float colred[4][E];
    __shared__ float lenred[4];
    const float* base = words + (size_t)(b * S + ch * 256) * E;
    float4 c0 = make_float4(0.f,0.f,0.f,0.f), c1 = make_float4(0.f,0.f,0.f,0.f);
    float wlen = 0.0f;
    for (int r = w; r < 256; r += 4) {
        const float* row = base + (size_t)r * E;
        float4 a  = *(const float4*)(row + 4*l);
        float4 bb = *(const float4*)(row + 256 + 4*l);
        float rs = a.x+a.y+a.z+a.w + bb.x+bb.y+bb.z+bb.w;
        #pragma unroll
        for (int m = 1; m < 64; m <<= 1) rs += __shfl_xor(rs, m);
        c0.x += a.x;  c0.y += a.y;  c0.z += a.z;  c0.w += a.w;
        c1.x += bb.x; c1.y += bb.y; c1.z += bb.z; c1.w += bb.w;
        if (l == 0) {
            float mv = (rs != 0.0f) ? 1.0f : 0.0f;
            mask[(size_t)b*S + ch*256 + r] = mv;
            wlen += mv;
        }
    }
    *(float4*)&colred[w][4*l]       = c0;
    *(float4*)&colred[w][256 + 4*l] = c1;
    if (l == 0) lenred[w] = wlen;
    __syncthreads();
    float s1 = colred[0][t]+colred[1][t]+colred[2][t]+colred[3][t];
    float s2 = colred[0][t+256]+colred[1][t+256]+colred[2][t+256]+colred[3][t+256];
    size_t o = ((size_t)ch * B + b) * E;
    ctxp[o + t]       = s1;
    ctxp[o + t + 256] = s2;
    if (t == 0) lenp[ch*B + b] = lenred[0]+lenred[1]+lenred[2]+lenred[3];
}

// ---------------------------------------------------------------------------
// K2: cb[b,h] = b_att[h] + context_b . W_att[E:, h]
// ---------------------------------------------------------------------------
__global__ __launch_bounds__(256)
void k2_cb(const float* __restrict__ W_att, const float* __restrict__ b_att,
           const float* __restrict__ ctxp, const float* __restrict__ lenp,
           float* __restrict__ cb)
{
    int bid = blockIdx.x;            // 128
    int b = bid >> 1, hc = bid & 1;
    int t = threadIdx.x;
    __shared__ float ctxL[E];
    float len = 0.f;
    #pragma unroll
    for (int k = 0; k < 8; ++k) len += lenp[k*B + b];
    float inv = 1.0f / len;
    for (int c = t; c < E; c += 256) {
        float sv = 0.f;
        #pragma unroll
        for (int k = 0; k < 8; ++k) sv += ctxp[((size_t)k*B + b)*E + c];
        ctxL[c] = sv * inv;
    }
    __syncthreads();
    int h = hc*256 + t;
    const float* Wb = W_att + (size_t)E * HD;
    float a0 = b_att[h], a1 = 0.f, a2 = 0.f, a3 = 0.f;
    #pragma unroll 4
    for (int e = 0; e < E; e += 4) {
        a0 += ctxL[e]   * Wb[(size_t)e*HD + h];
        a1 += ctxL[e+1] * Wb[(size_t)(e+1)*HD + h];
        a2 += ctxL[e+2] * Wb[(size_t)(e+2)*HD + h];
        a3 += ctxL[e+3] * Wb[(size_t)(e+3)*HD + h];
    }
    cb[(size_t)b*HD + h] = (a0 + a1) + (a2 + a3);
}

// ---------------------------------------------------------------------------
// K3: fp16 MFMA scores. Block tile 128(M) x 512(N) -> A read once.
// 8 waves = 2 wr x 4 wc, wave 64x128 -> acc[4][8] = 128 AGPR,
// 32 MFMA per wave per kstep (big window).
// A: LDS dbuf 2x8KB, conflict-free linear staging map, 3-kstep-deep loads.
// B: register double-buffer at KSTEP granularity: all 8 frags for kstep k+1
//    issued before kstep k's MFMAs -> ~full window (300+ cy) of L2 cover.
// One barrier per kstep. Writes complete raw scores.
// ---------------------------------------------------------------------------
__global__ __launch_bounds__(512, 2)
void k3_scores(const float* __restrict__ words,
               const unsigned short* __restrict__ Wpk,
               const float* __restrict__ cb, const float* __restrict__ v,
               float* __restrict__ sc)
{
    __shared__ __align__(16) unsigned char smem[16384];   // A dbuf: 2 x 8KB
    int mt = blockIdx.x;              // 1024 mtiles of 128 rows
    int m0 = mt * 128;
    int b  = m0 >> 11;                // S = 2048
    int t = threadIdx.x;
    int lane = t & 63, wid = t >> 6;
    int wr = wid >> 2, wc = wid & 3;  // 2 row-groups x 4 col-groups

    f32x4 acc[4][8];
    #pragma unroll
    for (int i = 0; i < 4; ++i)
        #pragma unroll
        for (int j = 0; j < 8; ++j) acc[i][j] = (f32x4)0.0f;

    // ---- A staging map (linear LDS pos p = t*16 bytes):
    // F = (t>>6)&7 (16-row frag), kb = (t>>4)&3, l15 = t&15;
    // row = F*16 + l15; k-offset within kstep = kb*8 (8 consecutive floats).
    int sF = (t >> 6) & 7, skb = (t >> 4) & 3, sl15 = t & 15;
    int srow = sF*16 + sl15;
    const float* aSrc = words + (size_t)(m0 + srow)*E + skb*8;

    // ---- B fragment base: frag fl = wc*8 + cf  (all 512 cols in-block)
    const unsigned short* bBase = Wpk + (((size_t)(wc*8))*64 + lane)*8;
#define LDB(kst,cf) (*(const short8*)(bBase + ((size_t)(kst)*32 + (cf))*512))

    float4 pa0, pa1, qa0, qa1;
#define LOADA(P0, P1, s) do { const float* _s = aSrc + (s)*32; \
        P0 = *(const float4*)(_s); P1 = *(const float4*)(_s + 4); } while(0)
#define STAGEA(buf, P0, P1) do { \
        unsigned int u0 = f2hu(P0.x) | (f2hu(P0.y) << 16); \
        unsigned int u1 = f2hu(P0.z) | (f2hu(P0.w) << 16); \
        unsigned int u2 = f2hu(P1.x) | (f2hu(P1.y) << 16); \
        unsigned int u3 = f2hu(P1.z) | (f2hu(P1.w) << 16); \
        *(uint4*)&(buf)[t*16] = make_uint4(u0, u1, u2, u3); } while(0)

    unsigned char* sm0 = smem;
    unsigned char* sm1 = smem + 8192;

    short8 bA[8], bB[8];

    // ---- prologue: stage kstep0 -> sm0; pa <- k1, qa <- k2; bA <- kstep0
    LOADA(pa0, pa1, 0);
    STAGEA(sm0, pa0, pa1);
    LOADA(pa0, pa1, 1);
    LOADA(qa0, qa1, 2);
    #pragma unroll
    for (int cf = 0; cf < 8; ++cf) bA[cf] = LDB(0, cf);
    __syncthreads();

    // kstep body: consume BUFC + BCUR; prefetch B(k+1)->BNEXT early;
    // stage A(k+1) into BUFN from P; refill P with A(k+3).
#define KBODY(k, BUFC, BUFN, P0, P1, BCUR, BNEXT) do { \
        short8 ah[4]; \
        _Pragma("unroll") \
        for (int rf = 0; rf < 4; ++rf) \
            ah[rf] = *(const short8*)&(BUFC)[(wr*4 + rf)*1024 + lane*16]; \
        if ((k) < 15) { \
            _Pragma("unroll") \
            for (int cf = 0; cf < 8; ++cf) BNEXT[cf] = LDB((k)+1, cf); \
            STAGEA(BUFN, P0, P1); \
        } \
        if ((k) < 13) LOADA(P0, P1, (k) + 3); \
        _Pragma("unroll") \
        for (int cf = 0; cf < 8; ++cf) { \
            _Pragma("unroll") \
            for (int rf = 0; rf < 4; ++rf) \
                acc[rf][cf] = __builtin_amdgcn_mfma_f32_16x16x32_f16(ah[rf], BCUR[cf], acc[rf][cf], 0, 0, 0); \
        } \
        __syncthreads(); } while(0)

    KBODY( 0, sm0, sm1, pa0, pa1, bA, bB);
    KBODY( 1, sm1, sm0, qa0, qa1, bB, bA);
    KBODY( 2, sm0, sm1, pa0, pa1, bA, bB);
    KBODY( 3, sm1, sm0, qa0, qa1, bB, bA);
    KBODY( 4, sm0, sm1, pa0, pa1, bA, bB);
    KBODY( 5, sm1, sm0, qa0, qa1, bB, bA);
    KBODY( 6, sm0, sm1, pa0, pa1, bA, bB);
    KBODY( 7, sm1, sm0, qa0, qa1, bB, bA);
    KBODY( 8, sm0, sm1, pa0, pa1, bA, bB);
    KBODY( 9, sm1, sm0, qa0, qa1, bB, bA);
    KBODY(10, sm0, sm1, pa0, pa1, bA, bB);
    KBODY(11, sm1, sm0, qa0, qa1, bB, bA);
    KBODY(12, sm0, sm1, pa0, pa1, bA, bB);
    KBODY(13, sm1, sm0, qa0, qa1, bB, bA);
    KBODY(14, sm0, sm1, pa0, pa1, bA, bB);
    KBODY(15, sm1, sm0, qa0, qa1, bB, bA);
#undef KBODY
#undef LOADA
#undef STAGEA
#undef LDB

    // ---- epilogue: tanh(+cb)*v, reduce over this wave's 128 cols
    float ssum[4][4];
    #pragma unroll
    for (int i = 0; i < 4; ++i)
        #pragma unroll
        for (int rr = 0; rr < 4; ++rr) ssum[i][rr] = 0.f;

    #pragma unroll
    for (int cf = 0; cf < 8; ++cf) {
        int col = wc*128 + cf*16 + (lane & 15);
        float cbv = cb[(size_t)b*HD + col];
        float vv  = v[col];
        #pragma unroll
        for (int rf = 0; rf < 4; ++rf)
            #pragma unroll
            for (int rr = 0; rr < 4; ++rr)
                ssum[rf][rr] += fast_tanh(acc[rf][cf][rr] + cbv) * vv;
    }
    #pragma unroll
    for (int m = 1; m < 16; m <<= 1)
        #pragma unroll
        for (int rf = 0; rf < 4; ++rf)
            #pragma unroll
            for (int rr = 0; rr < 4; ++rr)
                ssum[rf][rr] += __shfl_xor(ssum[rf][rr], m);

    float* scr = (float*)smem;   // 4 wc x 128 rows; loop ended with barrier
    if ((lane & 15) == 0) {
        #pragma unroll
        for (int rf = 0; rf < 4; ++rf)
            #pragma unroll
            for (int rr = 0; rr < 4; ++rr)
                scr[wc*128 + wr*64 + rf*16 + (lane >> 4)*4 + rr] = ssum[rf][rr];
    }
    __syncthreads();
    if (t < 128) {
        float val = (scr[t] + scr[128 + t]) + (scr[256 + t] + scr[384 + t]);
        sc[(size_t)m0 + t] = val;
    }
}

// ---------------------------------------------------------------------------
// K4 (fused softstats + rep): block (b, ch). Recompute batch softmax stats
// from sc (redundant x8, cheap L2 reads), then weighted col-sum of chunk.
// ---------------------------------------------------------------------------
__global__ __launch_bounds__(256)
void k4_rep(const float* __restrict__ words, const float* __restrict__ sc,
            const float* __restrict__ mask, float* __restrict__ repp)
{
    int bid = blockIdx.x;            // 512
    int b = bid >> 3, ch = bid & 7;
    int t = threadIdx.x;
    __shared__ float red[256];
    __shared__ float wrow[256];

    float xs[8];
    float mx = -1e30f;
    #pragma unroll
    for (int k = 0; k < 8; ++k) {
        size_t m = (size_t)b*S + 256*k + t;
        float x = sc[m];
        x = (mask[m] > 0.0f) ? x : -1e30f;
        xs[k] = x; mx = fmaxf(mx, x);
    }
    red[t] = mx; __syncthreads();
    for (int off = 128; off > 0; off >>= 1) {
        if (t < off) red[t] = fmaxf(red[t], red[t+off]);
        __syncthreads();
    }
    float gmax = red[0]; __syncthreads();
    float se = 0.f;
    #pragma unroll
    for (int k = 0; k < 8; ++k) se += expf(xs[k] - gmax);
    red[t] = se; __syncthreads();
    for (int off = 128; off > 0; off >>= 1) {
        if (t < off) red[t] += red[t+off];
        __syncthreads();
    }
    float den = red[0];
    wrow[t] = expf(xs[ch] - gmax) / den;    // this chunk's row weight
    __syncthreads();

    const float* base = words + (size_t)(b*S + ch*256)*E + 2*t;
    float2 acc = make_float2(0.f, 0.f);
    #pragma unroll 4
    for (int rr = 0; rr < 256; ++rr) {
        float2 wv = *(const float2*)(base + (size_t)rr*E);
        float a = wrow[rr];
        acc.x = fmaf(a, wv.x, acc.x);
        acc.y = fmaf(a, wv.y, acc.y);
    }
    size_t o = ((size_t)ch*B + b)*E + 2*t;
    *(float2*)&repp[o] = acc;
}

// ---------------------------------------------------------------------------
// K5 (fused MLP): one block per batch. LDS ping-pong between layers.
// ---------------------------------------------------------------------------
__global__ __launch_bounds__(256)
void k5_mlp(const float* __restrict__ repp,
            const float* __restrict__ W1, const float* __restrict__ b1,
            const float* __restrict__ W2, const float* __restrict__ b2,
            const float* __restrict__ W3, const float* __restrict__ b3,
            float* __restrict__ out)
{
    int b = blockIdx.x;              // 64
    int t = threadIdx.x;             // 256
    __shared__ float xL[HD];
    __shared__ float yL[HD];
    for (int c = t; c < E; c += 256) {
        float sv = 0.f;
        #pragma unroll
        for (int k = 0; k < 8; ++k) sv += repp[((size_t)k*B + b)*E + c];
        xL[c] = sv;
    }
    __syncthreads();
    #pragma unroll
    for (int oo = 0; oo < 2; ++oo) {
        int h = oo*256 + t;
        float a0 = b1[h], a1 = 0.f, a2 = 0.f, a3 = 0.f;
        #pragma unroll 4
        for (int e = 0; e < E; e += 4) {
            a0 += xL[e]   * W1[(size_t)e*HD + h];
            a1 += xL[e+1] * W1[(size_t)(e+1)*HD + h];
            a2 += xL[e+2] * W1[(size_t)(e+2)*HD + h];
            a3 += xL[e+3] * W1[(size_t)(e+3)*HD + h];
        }
        yL[h] = fmaxf((a0 + a1) + (a2 + a3), 0.f);
    }
    __syncthreads();
    float l2v[2];
    #pragma unroll
    for (int oo = 0; oo < 2; ++oo) {
        int h = oo*256 + t;
        float a0 = b2[h], a1 = 0.f, a2 = 0.f, a3 = 0.f;
        #pragma unroll 4
        for (int e = 0; e < HD; e += 4) {
            a0 += yL[e]   * W2[(size_t)e*HD + h];
            a1 += yL[e+1] * W2[(size_t)(e+1)*HD + h];
            a2 += yL[e+2] * W2[(size_t)(e+2)*HD + h];
            a3 += yL[e+3] * W2[(size_t)(e+3)*HD + h];
        }
        l2v[oo] = fmaxf((a0 + a1) + (a2 + a3), 0.f);
    }
    __syncthreads();
    xL[t] = l2v[0]; xL[256 + t] = l2v[1];
    __syncthreads();
    if (t < TD) {
        float a0 = b3[t], a1 = 0.f, a2 = 0.f, a3 = 0.f;
        #pragma unroll 4
        for (int e = 0; e < HD; e += 4) {
            a0 += xL[e]   * W3[(size_t)e*TD + t];
            a1 += xL[e+1] * W3[(size_t)(e+1)*TD + t];
            a2 += xL[e+2] * W3[(size_t)(e+2)*TD + t];
            a3 += xL[e+3] * W3[(size_t)(e+3)*TD + t];
        }
        out[(size_t)b*TD + t] = (a0 + a1) + (a2 + a3);
    }
}

extern "C" void kernel_launch(void* const* d_in, const int* in_sizes, int n_in,
                              void* d_out, int out_size, void* d_ws, size_t ws_size,
                              hipStream_t stream)
{
    const float* words = (const float*)d_in[0];
    const float* W_att = (const float*)d_in[1];
    const float* b_att = (const float*)d_in[2];
    const float* v     = (const float*)d_in[3];
    const float* W1    = (const float*)d_in[4];
    const float* b1    = (const float*)d_in[5];
    const float* W2    = (const float*)d_in[6];
    const float* b2    = (const float*)d_in[7];
    const float* W3    = (const float*)d_in[8];
    const float* b3    = (const float*)d_in[9];
    (void)in_sizes; (void)n_in; (void)out_size; (void)ws_size;

    float* ws   = (float*)d_ws;
    float* mask = ws + OFF_MASK;
    float* ctxp = ws + OFF_CTXP;
    float* lenp = ws + OFF_LENP;
    float* cb   = ws + OFF_CB;
    float* repp = ws + OFF_REPP;
    float* sc   = ws + OFF_SC;
    unsigned short* Wpk = (unsigned short*)(ws + OFF_WPK);
    float* out  = (float*)d_out;

    hipLaunchKernelGGL(k0_pack,    dim3(1024), dim3(256), 0, stream, W_att, Wpk);
    hipLaunchKernelGGL(k1_maskcol, dim3(B*8),  dim3(256), 0, stream, words, mask, ctxp, lenp);
    hipLaunchKernelGGL(k2_cb,      dim3(B*2),  dim3(256), 0, stream, W_att, b_att, ctxp, lenp, cb);
    hipLaunchKernelGGL(k3_scores,  dim3(1024), dim3(512), 0, stream, words, Wpk, cb, v, sc);
    hipLaunchKernelGGL(k4_rep,     dim3(B*8),  dim3(256), 0, stream, words, sc, mask, repp);
    hipLaunchKernelGGL(k5_mlp,     dim3(B),    dim3(256), 0, stream, repp, W1, b1, W2, b2, W3, b3, out);
}

// Round 9
// 308.507 us; speedup vs baseline: 1.1694x; 1.0441x over previous
//
#include <hip/hip_runtime.h>
#include <hip/hip_bf16.h>
#include <hip/hip_fp16.h>
#include <math.h>

// Problem dims
#define B 64
#define S 2048
#define E 512
#define HD 512
#define TD 128
#define M_TOT (B*S)
#define NCHUNK (M_TOT/128)      // 1024 k3 chunks (16 per batch)

// Workspace layout (in floats)
#define OFF_MASK   0                        // B*S
#define OFF_CTXP   (OFF_MASK + B*S)         // 8*B*E
#define OFF_LENP   (OFF_CTXP + 8*B*E)       // 8*B
#define OFF_CB     (OFF_LENP + 8*B)         // B*HD
#define OFF_PP     (OFF_CB + B*HD)          // NCHUNK*E   P partials
#define OFF_ML     (OFF_PP + NCHUNK*E)      // NCHUNK     local maxima
#define OFF_LL     (OFF_ML + NCHUNK)        // NCHUNK     local exp-sums
#define OFF_WPK    (OFF_LL + NCHUNK)        // 262144 fp16 = 131072 floats

typedef __attribute__((ext_vector_type(8))) short short8;
typedef __attribute__((ext_vector_type(4))) float f32x4;

__device__ inline unsigned int f2hu(float x) {
    __half h = __float2half(x);
    unsigned short u; __builtin_memcpy(&u, &h, 2); return (unsigned int)u;
}

// fast tanh: exact saturation, ~1e-6 rel err, no NaN (e in (0,1])
__device__ inline float fast_tanh(float x) {
    float a = fabsf(x);
    float e = __expf(-2.0f * a);
    float r = (1.0f - e) / (1.0f + e);
    return copysignf(r, x);
}

// ---------------------------------------------------------------------------
// k0: pack top half of W_att into MFMA B-fragment layout, fp16.
// ---------------------------------------------------------------------------
__global__ __launch_bounds__(256)
void k0_pack(const float* __restrict__ W_att, unsigned short* __restrict__ Wpk)
{
    int tid = blockIdx.x*256 + threadIdx.x;   // 262144 total
    int e = tid >> 9, h = tid & 511;
    float w = W_att[(size_t)e*HD + h];
    int kstep = e >> 5, kb = (e >> 3) & 3, j = e & 7, f = h >> 4, l15 = h & 15;
    size_t dst = ((((size_t)kstep*32 + f)*64) + kb*16 + l15)*8 + j;
    Wpk[dst] = (unsigned short)f2hu(w);
}

// ---------------------------------------------------------------------------
// K1: mask, column partial sums, lengths
// ---------------------------------------------------------------------------
__global__ __launch_bounds__(256)
void k1_maskcol(const float* __restrict__ words, float* __restrict__ mask,
                float* __restrict__ ctxp, float* __restrict__ lenp)
{
    int bid = blockIdx.x;            // 512 = B * 8
    int b = bid >> 3, ch = bid & 7;
    int t = threadIdx.x;
    int w = t >> 6, l = t & 63;
    __shared__ __align__(16) float colred[4][E];
    __shared__ float lenred[4];
    const float* base = words + (size_t)(b * S + ch * 256) * E;
    float4 c0 = make_float4(0.f,0.f,0.f,0.f), c1 = make_float4(0.f,0.f,0.f,0.f);
    float wlen = 0.0f;
    for (int r = w; r < 256; r += 4) {
        const float* row = base + (size_t)r * E;
        float4 a  = *(const float4*)(row + 4*l);
        float4 bb = *(const float4*)(row + 256 + 4*l);
        float rs = a.x+a.y+a.z+a.w + bb.x+bb.y+bb.z+bb.w;
        #pragma unroll
        for (int m = 1; m < 64; m <<= 1) rs += __shfl_xor(rs, m);
        c0.x += a.x;  c0.y += a.y;  c0.z += a.z;  c0.w += a.w;
        c1.x += bb.x; c1.y += bb.y; c1.z += bb.z; c1.w += bb.w;
        if (l == 0) {
            float mv = (rs != 0.0f) ? 1.0f : 0.0f;
            mask[(size_t)b*S + ch*256 + r] = mv;
            wlen += mv;
        }
    }
    *(float4*)&colred[w][4*l]       = c0;
    *(float4*)&colred[w][256 + 4*l] = c1;
    if (l == 0) lenred[w] = wlen;
    __syncthreads();
    float s1 = colred[0][t]+colred[1][t]+colred[2][t]+colred[3][t];
    float s2 = colred[0][t+256]+colred[1][t+256]+colred[2][t+256]+colred[3][t+256];
    size_t o = ((size_t)ch * B + b) * E;
    ctxp[o + t]       = s1;
    ctxp[o + t + 256] = s2;
    if (t == 0) lenp[ch*B + b] = lenred[0]+lenred[1]+lenred[2]+lenred[3];
}

// ---------------------------------------------------------------------------
// K2: cb[b,h] = b_att[h] + context_b . W_att[E:, h]
// ---------------------------------------------------------------------------
__global__ __launch_bounds__(256)
void k2_cb(const float* __restrict__ W_att, const float* __restrict__ b_att,
           const float* __restrict__ ctxp, const float* __restrict__ lenp,
           float* __restrict__ cb)
{
    int bid = blockIdx.x;            // 128
    int b = bid >> 1, hc = bid & 1;
    int t = threadIdx.x;
    __shared__ float ctxL[E];
    float len = 0.f;
    #pragma unroll
    for (int k = 0; k < 8; ++k) len += lenp[k*B + b];
    float inv = 1.0f / len;
    for (int c = t; c < E; c += 256) {
        float sv = 0.f;
        #pragma unroll
        for (int k = 0; k < 8; ++k) sv += ctxp[((size_t)k*B + b)*E + c];
        ctxL[c] = sv * inv;
    }
    __syncthreads();
    int h = hc*256 + t;
    const float* Wb = W_att + (size_t)E * HD;
    float a0 = b_att[h], a1 = 0.f, a2 = 0.f, a3 = 0.f;
    #pragma unroll 4
    for (int e = 0; e < E; e += 4) {
        a0 += ctxL[e]   * Wb[(size_t)e*HD + h];
        a1 += ctxL[e+1] * Wb[(size_t)(e+1)*HD + h];
        a2 += ctxL[e+2] * Wb[(size_t)(e+2)*HD + h];
        a3 += ctxL[e+3] * Wb[(size_t)(e+3)*HD + h];
    }
    cb[(size_t)b*HD + h] = (a0 + a1) + (a2 + a3);
}

// ---------------------------------------------------------------------------
// K3: fp16 MFMA scores + FUSED local softmax + P-partials (flash-style).
// Block tile 128(M) x 512(N), 8 waves (2wr x 4wc), wave 64x128, acc[4][8].
// Core identical to round 8. Epilogue: row scores -> masked local max m_c,
// exp-sum l_c, and P_c[e] = sum_r exp(sc_r - m_c) * words[r][e] (L2-hot
// re-read of this block's own tile). No sc array, no separate rep pass.
// ---------------------------------------------------------------------------
__global__ __launch_bounds__(512, 2)
void k3_scores(const float* __restrict__ words,
               const unsigned short* __restrict__ Wpk,
               const float* __restrict__ cb, const float* __restrict__ v,
               const float* __restrict__ mask,
               float* __restrict__ Pp, float* __restrict__ Ml, float* __restrict__ Ll)
{
    __shared__ __align__(16) unsigned char smem[16384];   // A dbuf: 2 x 8KB
    int mt = blockIdx.x;              // 1024 mtiles of 128 rows
    int m0 = mt * 128;
    int b  = m0 >> 11;                // S = 2048
    int t = threadIdx.x;
    int lane = t & 63, wid = t >> 6;
    int wr = wid >> 2, wc = wid & 3;  // 2 row-groups x 4 col-groups

    f32x4 acc[4][8];
    #pragma unroll
    for (int i = 0; i < 4; ++i)
        #pragma unroll
        for (int j = 0; j < 8; ++j) acc[i][j] = (f32x4)0.0f;

    // ---- A staging map (linear LDS pos p = t*16 bytes): conflict-free
    int sF = (t >> 6) & 7, skb = (t >> 4) & 3, sl15 = t & 15;
    int srow = sF*16 + sl15;
    const float* aSrc = words + (size_t)(m0 + srow)*E + skb*8;

    // ---- B fragment base: frag fl = wc*8 + cf  (all 512 cols in-block)
    const unsigned short* bBase = Wpk + (((size_t)(wc*8))*64 + lane)*8;
#define LDB(kst,cf) (*(const short8*)(bBase + ((size_t)(kst)*32 + (cf))*512))

    float4 pa0, pa1, qa0, qa1;
#define LOADA(P0, P1, s) do { const float* _s = aSrc + (s)*32; \
        P0 = *(const float4*)(_s); P1 = *(const float4*)(_s + 4); } while(0)
#define STAGEA(buf, P0, P1) do { \
        unsigned int u0 = f2hu(P0.x) | (f2hu(P0.y) << 16); \
        unsigned int u1 = f2hu(P0.z) | (f2hu(P0.w) << 16); \
        unsigned int u2 = f2hu(P1.x) | (f2hu(P1.y) << 16); \
        unsigned int u3 = f2hu(P1.z) | (f2hu(P1.w) << 16); \
        *(uint4*)&(buf)[t*16] = make_uint4(u0, u1, u2, u3); } while(0)

    unsigned char* sm0 = smem;
    unsigned char* sm1 = smem + 8192;

    short8 bA[8], bB[8];

    // ---- prologue
    LOADA(pa0, pa1, 0);
    STAGEA(sm0, pa0, pa1);
    LOADA(pa0, pa1, 1);
    LOADA(qa0, qa1, 2);
    #pragma unroll
    for (int cf = 0; cf < 8; ++cf) bA[cf] = LDB(0, cf);
    __syncthreads();

#define KBODY(k, BUFC, BUFN, P0, P1, BCUR, BNEXT) do { \
        short8 ah[4]; \
        _Pragma("unroll") \
        for (int rf = 0; rf < 4; ++rf) \
            ah[rf] = *(const short8*)&(BUFC)[(wr*4 + rf)*1024 + lane*16]; \
        if ((k) < 15) { \
            _Pragma("unroll") \
            for (int cf = 0; cf < 8; ++cf) BNEXT[cf] = LDB((k)+1, cf); \
            STAGEA(BUFN, P0, P1); \
        } \
        if ((k) < 13) LOADA(P0, P1, (k) + 3); \
        _Pragma("unroll") \
        for (int cf = 0; cf < 8; ++cf) { \
            _Pragma("unroll") \
            for (int rf = 0; rf < 4; ++rf) \
                acc[rf][cf] = __builtin_amdgcn_mfma_f32_16x16x32_f16(ah[rf], BCUR[cf], acc[rf][cf], 0, 0, 0); \
        } \
        __syncthreads(); } while(0)

    KBODY( 0, sm0, sm1, pa0, pa1, bA, bB);
    KBODY( 1, sm1, sm0, qa0, qa1, bB, bA);
    KBODY( 2, sm0, sm1, pa0, pa1, bA, bB);
    KBODY( 3, sm1, sm0, qa0, qa1, bB, bA);
    KBODY( 4, sm0, sm1, pa0, pa1, bA, bB);
    KBODY( 5, sm1, sm0, qa0, qa1, bB, bA);
    KBODY( 6, sm0, sm1, pa0, pa1, bA, bB);
    KBODY( 7, sm1, sm0, qa0, qa1, bB, bA);
    KBODY( 8, sm0, sm1, pa0, pa1, bA, bB);
    KBODY( 9, sm1, sm0, qa0, qa1, bB, bA);
    KBODY(10, sm0, sm1, pa0, pa1, bA, bB);
    KBODY(11, sm1, sm0, qa0, qa1, bB, bA);
    KBODY(12, sm0, sm1, pa0, pa1, bA, bB);
    KBODY(13, sm1, sm0, qa0, qa1, bB, bA);
    KBODY(14, sm0, sm1, pa0, pa1, bA, bB);
    KBODY(15, sm1, sm0, qa0, qa1, bB, bA);
#undef KBODY
#undef LOADA
#undef STAGEA
#undef LDB

    // ---- epilogue 1: tanh(+cb)*v, reduce to per-row raw scores
    float ssum[4][4];
    #pragma unroll
    for (int i = 0; i < 4; ++i)
        #pragma unroll
        for (int rr = 0; rr < 4; ++rr) ssum[i][rr] = 0.f;

    #pragma unroll
    for (int cf = 0; cf < 8; ++cf) {
        int col = wc*128 + cf*16 + (lane & 15);
        float cbv = cb[(size_t)b*HD + col];
        float vv  = v[col];
        #pragma unroll
        for (int rf = 0; rf < 4; ++rf)
            #pragma unroll
            for (int rr = 0; rr < 4; ++rr)
                ssum[rf][rr] += fast_tanh(acc[rf][cf][rr] + cbv) * vv;
    }
    #pragma unroll
    for (int m = 1; m < 16; m <<= 1)
        #pragma unroll
        for (int rf = 0; rf < 4; ++rf)
            #pragma unroll
            for (int rr = 0; rr < 4; ++rr)
                ssum[rf][rr] += __shfl_xor(ssum[rf][rr], m);

    float* fsm = (float*)smem;          // LDS float view (4096 floats avail)
    float* scr   = fsm;                 // [512]  per-wc partials
    float* scm   = fsm + 512;           // [128]  masked row scores
    float* wrow  = fsm + 640;           // [128]  row weights exp(sc - m_c)
    float* redv  = fsm + 768;           // [2]    m_c, l_c

    if ((lane & 15) == 0) {
        #pragma unroll
        for (int rf = 0; rf < 4; ++rf)
            #pragma unroll
            for (int rr = 0; rr < 4; ++rr)
                scr[wc*128 + wr*64 + rf*16 + (lane >> 4)*4 + rr] = ssum[rf][rr];
    }
    __syncthreads();

    // ---- epilogue 2: masked scores, local max
    if (t < 128) {
        float val = (scr[t] + scr[128 + t]) + (scr[256 + t] + scr[384 + t]);
        float mk = mask[(size_t)m0 + t];
        scm[t] = (mk > 0.0f) ? val : -1e30f;
    }
    __syncthreads();
    if (t < 64) {
        float m1 = fmaxf(scm[t], scm[t + 64]);
        #pragma unroll
        for (int mm = 1; mm < 64; mm <<= 1) m1 = fmaxf(m1, __shfl_xor(m1, mm));
        if (t == 0) redv[0] = m1;
    }
    __syncthreads();
    float m_c = redv[0];
    if (t < 128) wrow[t] = __expf(scm[t] - m_c);
    __syncthreads();
    if (t < 64) {
        float s1 = wrow[t] + wrow[t + 64];
        #pragma unroll
        for (int mm = 1; mm < 64; mm <<= 1) s1 += __shfl_xor(s1, mm);
        if (t == 0) redv[1] = s1;
    }

    // ---- epilogue 3: P_c[e] = sum_r wrow[r] * words[m0+r][e]  (L2-hot tile)
    float P = 0.f;
    const float* wbase = words + (size_t)m0*E + t;    // column t, 512 threads = 512 cols
    #pragma unroll 8
    for (int r2 = 0; r2 < 128; ++r2)
        P = fmaf(wrow[r2], wbase[(size_t)r2*E], P);
    __syncthreads();   // ensure redv[1] written
    Pp[(size_t)mt*E + t] = P;
    if (t == 0) { Ml[mt] = m_c; Ll[mt] = redv[1]; }
}

// ---------------------------------------------------------------------------
// K5 (combine + fused MLP): one block per batch. Prologue combines the 16
// chunk partials (flash-softmax identity) into rep, then 3-layer MLP.
// ---------------------------------------------------------------------------
__global__ __launch_bounds__(256)
void k5_mlp(const float* __restrict__ Pp, const float* __restrict__ Ml,
            const float* __restrict__ Ll,
            const float* __restrict__ W1, const float* __restrict__ b1,
            const float* __restrict__ W2, const float* __restrict__ b2,
            const float* __restrict__ W3, const float* __restrict__ b3,
            float* __restrict__ out)
{
    int b = blockIdx.x;              // 64
    int t = threadIdx.x;             // 256
    __shared__ float xL[HD];
    __shared__ float yL[HD];
    __shared__ float wf[16];

    if (t == 0) {
        float M = -3e38f;
        #pragma unroll
        for (int c = 0; c < 16; ++c) M = fmaxf(M, Ml[b*16 + c]);
        float den = 0.f;
        #pragma unroll
        for (int c = 0; c < 16; ++c) den += __expf(Ml[b*16 + c] - M) * Ll[b*16 + c];
        float inv = 1.0f / den;
        #pragma unroll
        for (int c = 0; c < 16; ++c) wf[c] = __expf(Ml[b*16 + c] - M) * inv;
    }
    __syncthreads();

    #pragma unroll
    for (int oo = 0; oo < 2; ++oo) {
        int e = oo*256 + t;
        float sv = 0.f;
        #pragma unroll
        for (int c = 0; c < 16; ++c)
            sv += wf[c] * Pp[(size_t)(b*16 + c)*E + e];
        xL[e] = sv;
    }
    __syncthreads();
    #pragma unroll
    for (int oo = 0; oo < 2; ++oo) {
        int h = oo*256 + t;
        float a0 = b1[h], a1 = 0.f, a2 = 0.f, a3 = 0.f;
        #pragma unroll 4
        for (int e = 0; e < E; e += 4) {
            a0 += xL[e]   * W1[(size_t)e*HD + h];
            a1 += xL[e+1] * W1[(size_t)(e+1)*HD + h];
            a2 += xL[e+2] * W1[(size_t)(e+2)*HD + h];
            a3 += xL[e+3] * W1[(size_t)(e+3)*HD + h];
        }
        yL[h] = fmaxf((a0 + a1) + (a2 + a3), 0.f);
    }
    __syncthreads();
    float l2v[2];
    #pragma unroll
    for (int oo = 0; oo < 2; ++oo) {
        int h = oo*256 + t;
        float a0 = b2[h], a1 = 0.f, a2 = 0.f, a3 = 0.f;
        #pragma unroll 4
        for (int e = 0; e < HD; e += 4) {
            a0 += yL[e]   * W2[(size_t)e*HD + h];
            a1 += yL[e+1] * W2[(size_t)(e+1)*HD + h];
            a2 += yL[e+2] * W2[(size_t)(e+2)*HD + h];
            a3 += yL[e+3] * W2[(size_t)(e+3)*HD + h];
        }
        l2v[oo] = fmaxf((a0 + a1) + (a2 + a3), 0.f);
    }
    __syncthreads();
    xL[t] = l2v[0]; xL[256 + t] = l2v[1];
    __syncthreads();
    if (t < TD) {
        float a0 = b3[t], a1 = 0.f, a2 = 0.f, a3 = 0.f;
        #pragma unroll 4
        for (int e = 0; e < HD; e += 4) {
            a0 += xL[e]   * W3[(size_t)e*TD + t];
            a1 += xL[e+1] * W3[(size_t)(e+1)*TD + t];
            a2 += xL[e+2] * W3[(size_t)(e+2)*TD + t];
            a3 += xL[e+3] * W3[(size_t)(e+3)*TD + t];
        }
        out[(size_t)b*TD + t] = (a0 + a1) + (a2 + a3);
    }
}

extern "C" void kernel_launch(void* const* d_in, const int* in_sizes, int n_in,
                              void* d_out, int out_size, void* d_ws, size_t ws_size,
                              hipStream_t stream)
{
    const float* words = (const float*)d_in[0];
    const float* W_att = (const float*)d_in[1];
    const float* b_att = (const float*)d_in[2];
    const float* v     = (const float*)d_in[3];
    const float* W1    = (const float*)d_in[4];
    const float* b1    = (const float*)d_in[5];
    const float* W2    = (const float*)d_in[6];
    const float* b2    = (const float*)d_in[7];
    const float* W3    = (const float*)d_in[8];
    const float* b3    = (const float*)d_in[9];
    (void)in_sizes; (void)n_in; (void)out_size; (void)ws_size;

    float* ws   = (float*)d_ws;
    float* mask = ws + OFF_MASK;
    float* ctxp = ws + OFF_CTXP;
    float* lenp = ws + OFF_LENP;
    float* cb   = ws + OFF_CB;
    float* Pp   = ws + OFF_PP;
    float* Ml   = ws + OFF_ML;
    float* Ll   = ws + OFF_LL;
    unsigned short* Wpk = (unsigned short*)(ws + OFF_WPK);
    float* out  = (float*)d_out;

    hipLaunchKernelGGL(k0_pack,    dim3(1024), dim3(256), 0, stream, W_att, Wpk);
    hipLaunchKernelGGL(k1_maskcol, dim3(B*8),  dim3(256), 0, stream, words, mask, ctxp, lenp);
    hipLaunchKernelGGL(k2_cb,      dim3(B*2),  dim3(256), 0, stream, W_att, b_att, ctxp, lenp, cb);
    hipLaunchKernelGGL(k3_scores,  dim3(1024), dim3(512), 0, stream, words, Wpk, cb, v, mask, Pp, Ml, Ll);
    hipLaunchKernelGGL(k5_mlp,     dim3(B),    dim3(256), 0, stream, Pp, Ml, Ll, W1, b1, W2, b2, W3, b3, out);
}